// Round 5
// baseline (5257.623 us; speedup 1.0000x reference)
//
#include <hip/hip_runtime.h>

// Neural-ODE RK4 over MLP 12->300->100->50->12, B=1024, T=100.
// 512 blocks x 512 threads, 2 batch elements per block -> 2 blocks/CU
// (independent barrier domains overlap each other's stalls).
// W1/W2 in registers (distributed), W3/W4 in LDS. Activations broadcast
// from LDS with compile-time offsets. All hot loops use packed fp32 FMA
// (v_pk_fma_f32 via __builtin_elementwise_fma on float2).

typedef float v2f __attribute__((ext_vector_type(2)));
typedef float v4f __attribute__((ext_vector_type(4)));

constexpr int TT = 100;
constexpr int D  = 12;
constexpr int H1 = 300;
constexpr int H2 = 100;
constexpr int H3 = 50;
constexpr float NEG = 0.01f;

__device__ __forceinline__ float lrelu(float x) { return fmaxf(x, NEG * x); }
__device__ __forceinline__ v2f lo2(v4f v) { return __builtin_shufflevector(v, v, 0, 1); }
__device__ __forceinline__ v2f hi2(v4f v) { return __builtin_shufflevector(v, v, 2, 3); }
__device__ __forceinline__ v2f pkfma(v2f a, v2f b, v2f c) {
#if __has_builtin(__builtin_elementwise_fma)
    return __builtin_elementwise_fma(a, b, c);
#else
    return a * b + c;   // HIP default fp-contract -> fma
#endif
}

__global__ __launch_bounds__(512, 4)
void node_rk4_kernel(const float* __restrict__ y0, const float* __restrict__ t,
                     const float* __restrict__ W1, const float* __restrict__ b1,
                     const float* __restrict__ W2, const float* __restrict__ b2,
                     const float* __restrict__ W3, const float* __restrict__ b3,
                     const float* __restrict__ W4, const float* __restrict__ b4,
                     float* __restrict__ out)
{
    // LDS ~ 37 KB -> 2 blocks/CU easily
    __shared__ __align__(16) float sW3c[25 * 200];   // [c][j][4k] chunked W3
    __shared__ __align__(16) float sW4 [52 * 12];    // [k][j], rows 50,51 zero
    __shared__ __align__(16) float h1  [2 * 320];    // pitch 320; k 300..319 zero
    __shared__ __align__(16) float pL2 [16 * 104];   // [(kq8*2+e)][104]
    __shared__ __align__(16) float h2  [2 * 104];
    __shared__ __align__(16) float pL3 [8 * 52];     // [(q*2+e)][52]
    __shared__ __align__(16) float h3  [2 * 52];     // cols 50,51 zero
    __shared__ __align__(16) float sx  [24];
    __shared__ __align__(16) float sxe [24];
    __shared__ __align__(16) float sks [24];
    __shared__ float sb2[100];
    __shared__ float sb3[52];
    __shared__ float st [100];

    const int tid = threadIdx.x;
    const int l   = tid & 63;
    const int w   = tid >> 6;            // wave 0..7 = L2 k-eighth
    const bool c2 = (l < 50);
    const int  j0 = c2 ? l : 0;          // L2 col0 (col1 = j0+50)

    // ---- register-resident W2: lane owns cols (j0, j0+50), k-eighth w ----
    v4f w2a[10], w2b[10];
#pragma unroll
    for (int i = 0; i < 10; ++i) {
        const int c = w + 8 * i;         // chunk of 4 k-values, c < 80
#pragma unroll
        for (int jj = 0; jj < 4; ++jj) {
            const int k = c * 4 + jj;
            float va = 0.0f, vb = 0.0f;
            if (c2 && k < H1) { va = W2[k * H2 + j0]; vb = W2[k * H2 + j0 + 50]; }
            w2a[i][jj] = va; w2b[i][jj] = vb;
        }
    }
    // ---- register-resident W1 (col = tid) ----
    v4f w1v[3];
    float rb1 = 0.0f;
#pragma unroll
    for (int q = 0; q < 3; ++q) w1v[q] = v4f{0.f, 0.f, 0.f, 0.f};
    if (tid < H1) {
        rb1 = b1[tid];
#pragma unroll
        for (int q = 0; q < 3; ++q)
#pragma unroll
            for (int jj = 0; jj < 4; ++jj) w1v[q][jj] = W1[(q * 4 + jj) * H1 + tid];
    }
    // ---- L4 lane mapping (waves 4-5, 96 threads) ----
    const int u4 = tid - 256;
    const bool l4act = (u4 >= 0 && u4 < 96);
    int e4 = 0, j4 = 0, kq4 = 0;
    float b4v = 0.0f;
    if (l4act) {
        e4 = u4 / 48; const int r = u4 - e4 * 48; j4 = r >> 2; kq4 = r & 3;
        b4v = b4[j4];
    }

    // ---- LDS staging (one-time) ----
    for (int i = tid; i < H2 * H3; i += 512) {       // W3 [k=100][j=50] -> chunked
        const int k = i / H3, j = i - k * H3;
        sW3c[(k >> 2) * 200 + j * 4 + (k & 3)] = W3[i];
    }
    for (int i = tid; i < 52 * 12; i += 512) sW4[i] = (i < H3 * D) ? W4[i] : 0.0f;
    if (tid < H2) sb2[tid] = b2[tid];
    if (tid < 52) sb3[tid] = (tid < H3) ? b3[tid] : 0.0f;
    if (tid < TT) st[tid] = t[tid];                  // t row 0 (uniform over batch)
    if (tid >= 64 && tid < 104) {                    // zero h1 pad k=300..319
        const int u = tid - 64, e = u / 20, kk = u - e * 20;
        h1[e * 320 + 300 + kk] = 0.0f;
    }
    if (tid >= 104 && tid < 108) {                   // zero h3 pad
        const int u = tid - 104;
        h3[(u >> 1) * 52 + 50 + (u & 1)] = 0.0f;
    }
    if (tid < 24) {                                  // x0 = y0[:,0,:]; out[:,0,:]
        const int e = tid / 12, j = tid - e * 12;
        const int g = (blockIdx.x * 2 + e) * (TT * D) + j;
        const float v = y0[g];
        sx[tid] = v;
        out[g]  = v;
    }
    __syncthreads();

    for (int s = 0; s < TT - 1; ++s) {
        const float dt = st[s + 1] - st[s];
#pragma unroll 1
        for (int ev = 0; ev < 4; ++ev) {
            const float* xin = ev ? sxe : sx;

            // ===== L1: 12 -> 300, col = tid, reg weights, packed =====
            if (tid < H1) {
#pragma unroll
                for (int e = 0; e < 2; ++e) {
                    const v4f x0 = *(const v4f*)(xin + e * 12);
                    const v4f x1 = *(const v4f*)(xin + e * 12 + 4);
                    const v4f x2 = *(const v4f*)(xin + e * 12 + 8);
                    v2f a = {rb1, 0.0f};
                    a = pkfma(lo2(x0), lo2(w1v[0]), a); a = pkfma(hi2(x0), hi2(w1v[0]), a);
                    a = pkfma(lo2(x1), lo2(w1v[1]), a); a = pkfma(hi2(x1), hi2(w1v[1]), a);
                    a = pkfma(lo2(x2), lo2(w1v[2]), a); a = pkfma(hi2(x2), hi2(w1v[2]), a);
                    h1[e * 320 + tid] = lrelu(a.x + a.y);
                }
            }
            __syncthreads();                         // A: h1 ready

            // ===== L2: 300 -> 100, reg weights, broadcast reads, packed =====
            {
                v2f a00 = {0,0}, a01 = {0,0}, a10 = {0,0}, a11 = {0,0};
#pragma unroll
                for (int i = 0; i < 10; ++i) {
                    const int c4 = (w + 8 * i) * 4;
                    const v4f he0 = *(const v4f*)(h1 + c4);          // elem 0
                    const v4f he1 = *(const v4f*)(h1 + 320 + c4);    // elem 1
                    a00 = pkfma(lo2(he0), lo2(w2a[i]), a00);
                    a00 = pkfma(hi2(he0), hi2(w2a[i]), a00);
                    a01 = pkfma(lo2(he0), lo2(w2b[i]), a01);
                    a01 = pkfma(hi2(he0), hi2(w2b[i]), a01);
                    a10 = pkfma(lo2(he1), lo2(w2a[i]), a10);
                    a10 = pkfma(hi2(he1), hi2(w2a[i]), a10);
                    a11 = pkfma(lo2(he1), lo2(w2b[i]), a11);
                    a11 = pkfma(hi2(he1), hi2(w2b[i]), a11);
                }
                if (c2) {
                    pL2[(w * 2 + 0) * 104 + j0]      = a00.x + a00.y;
                    pL2[(w * 2 + 0) * 104 + j0 + 50] = a01.x + a01.y;
                    pL2[(w * 2 + 1) * 104 + j0]      = a10.x + a10.y;
                    pL2[(w * 2 + 1) * 104 + j0 + 50] = a11.x + a11.y;
                }
            }
            __syncthreads();                         // B: partials ready

            // ===== reduce -> h2 (8-way), waves 4-7 =====
            {
                const int u = tid - 256;
                if (u >= 0 && u < 200) {
                    const int e = u / 100, j = u - e * 100;
                    float v = sb2[j];
#pragma unroll
                    for (int q = 0; q < 8; ++q) v += pL2[(q * 2 + e) * 104 + j];
                    h2[e * 104 + j] = lrelu(v);
                }
            }
            __syncthreads();                         // C: h2 ready

            // ===== L3: 100 -> 50, waves 0-3 = k-quarters, LDS W3, packed =====
            if (w < 4 && c2) {
                v2f a0 = {0,0}, a1 = {0,0};
                for (int c = w; c < 25; c += 4) {
                    const v4f wv  = *(const v4f*)(sW3c + c * 200 + l * 4);
                    const v4f hv0 = *(const v4f*)(h2 + c * 4);
                    const v4f hv1 = *(const v4f*)(h2 + 104 + c * 4);
                    a0 = pkfma(lo2(hv0), lo2(wv), a0); a0 = pkfma(hi2(hv0), hi2(wv), a0);
                    a1 = pkfma(lo2(hv1), lo2(wv), a1); a1 = pkfma(hi2(hv1), hi2(wv), a1);
                }
                pL3[(w * 2 + 0) * 52 + l] = a0.x + a0.y;
                pL3[(w * 2 + 1) * 52 + l] = a1.x + a1.y;
            }
            __syncthreads();                         // D: pL3 ready

            // ===== reduce -> h3 (4-way), waves 6-7 =====
            {
                const int u = tid - 384;
                if (u >= 0 && u < 100) {
                    const int e = u / 50, j = u - e * 50;
                    float v = sb3[j];
#pragma unroll
                    for (int q = 0; q < 4; ++q) v += pL3[(q * 2 + e) * 52 + j];
                    h3[e * 52 + j] = lrelu(v);
                }
            }
            __syncthreads();                         // E: h3 ready

            // ===== L4: 50 -> 12, waves 4-5, shfl reduce, fused RK4 =====
            if (l4act) {
                const int kb = kq4 * 13;
                float a = 0.0f;
#pragma unroll
                for (int i = 0; i < 13; ++i)         // k<=51: h3/sW4 pads are zero
                    a = fmaf(h3[e4 * 52 + kb + i], sW4[(kb + i) * 12 + j4], a);
                a += __shfl_xor(a, 1);
                a += __shfl_xor(a, 2);
                if (kq4 == 0) {
                    a += b4v;
                    const int bi = e4 * 12 + j4;
                    const float xc = sx[bi];
                    if (ev == 0)      { sks[bi] = a;         sxe[bi] = xc + 0.5f * dt * a; }
                    else if (ev == 1) { sks[bi] += 2.f * a;  sxe[bi] = xc + 0.5f * dt * a; }
                    else if (ev == 2) { sks[bi] += 2.f * a;  sxe[bi] = xc + dt * a; }
                    else {
                        const float xn = xc + dt * (1.0f / 6.0f) * (sks[bi] + a);
                        sx[bi] = xn;
                        out[(blockIdx.x * 2 + e4) * (TT * D) + (s + 1) * D + j4] = xn;
                    }
                }
            }
            __syncthreads();                         // F: state ready
        }
    }
}

extern "C" void kernel_launch(void* const* d_in, const int* in_sizes, int n_in,
                              void* d_out, int out_size, void* d_ws, size_t ws_size,
                              hipStream_t stream) {
    const float* y0 = (const float*)d_in[0];
    const float* t  = (const float*)d_in[1];
    const float* W1 = (const float*)d_in[2];
    const float* b1 = (const float*)d_in[3];
    const float* W2 = (const float*)d_in[4];
    const float* b2 = (const float*)d_in[5];
    const float* W3 = (const float*)d_in[6];
    const float* b3 = (const float*)d_in[7];
    const float* W4 = (const float*)d_in[8];
    const float* b4 = (const float*)d_in[9];
    float* out = (float*)d_out;

    node_rk4_kernel<<<512, 512, 0, stream>>>(y0, t, W1, b1, W2, b2, W3, b3, W4, b4, out);
}

// Round 6
// 1530.555 us; speedup vs baseline: 3.4351x; 3.4351x over previous
//
#include <hip/hip_runtime.h>

// Neural-ODE RK4 over MLP 12->300->100->50->12, B=1024, T=100.
// 512 blocks x 512 threads, 2 batch elements per block -> 2 blocks/CU
// (independent barrier domains overlap each other's stalls).
// W2 in registers (80/thread, distributed over 8 k-eighth waves x 2 cols),
// W1/W3/W4 in LDS. Activations broadcast from LDS (uniform-address reads,
// compile-time offsets). Packed fp32 FMA (v_pk_fma_f32) in L2/L3.
// __launch_bounds__(512,2): observed CUDA semantics (min blocks/CU) ->
// VGPR cap 128, no spill (round-5 lesson: (512,4) capped at 64 and spilled).

typedef float v2f __attribute__((ext_vector_type(2)));
typedef float v4f __attribute__((ext_vector_type(4)));

constexpr int TT = 100;
constexpr int D  = 12;
constexpr int H1 = 300;
constexpr int H2 = 100;
constexpr int H3 = 50;
constexpr float NEG = 0.01f;

__device__ __forceinline__ float lrelu(float x) { return fmaxf(x, NEG * x); }
__device__ __forceinline__ v2f lo2(v4f v) { return __builtin_shufflevector(v, v, 0, 1); }
__device__ __forceinline__ v2f hi2(v4f v) { return __builtin_shufflevector(v, v, 2, 3); }
__device__ __forceinline__ v2f pkfma(v2f a, v2f b, v2f c) {
#if __has_builtin(__builtin_elementwise_fma)
    return __builtin_elementwise_fma(a, b, c);
#else
    return a * b + c;   // HIP default fp-contract -> fma
#endif
}

__global__ __launch_bounds__(512, 2)
void node_rk4_kernel(const float* __restrict__ y0, const float* __restrict__ t,
                     const float* __restrict__ W1, const float* __restrict__ b1,
                     const float* __restrict__ W2, const float* __restrict__ b2,
                     const float* __restrict__ W3, const float* __restrict__ b3,
                     const float* __restrict__ W4, const float* __restrict__ b4,
                     float* __restrict__ out)
{
    // LDS ~ 51.5 KB -> exactly 2 blocks/CU (with VGPR <= 128)
    __shared__ __align__(16) float sW1 [D * H1];     // [k][j] (14.4 KB)
    __shared__ __align__(16) float sW3c[25 * 200];   // [c][j][4k] chunked W3
    __shared__ __align__(16) float sW4 [52 * 12];    // [k][j], rows 50,51 zero
    __shared__ __align__(16) float h1  [2 * 320];    // pitch 320; k 300..319 zero
    __shared__ __align__(16) float pL2 [16 * 104];   // [(w*2+e)][104]
    __shared__ __align__(16) float h2  [2 * 104];
    __shared__ __align__(16) float pL3 [8 * 52];     // [(q*2+e)][52]
    __shared__ __align__(16) float h3  [2 * 52];     // cols 50,51 zero
    __shared__ __align__(16) float sx  [24];
    __shared__ __align__(16) float sxe [24];
    __shared__ __align__(16) float sks [24];
    __shared__ float sb1[300];
    __shared__ float sb2[100];
    __shared__ float sb3[52];
    __shared__ float st [100];

    const int tid = threadIdx.x;
    const int l   = tid & 63;
    const int w   = tid >> 6;            // wave 0..7 = L2 k-eighth
    const bool c2 = (l < 50);
    const int  j0 = c2 ? l : 0;          // L2 col0 (col1 = j0+50)

    // ---- register-resident W2: lane owns cols (j0, j0+50), k-eighth w ----
    v4f w2a[10], w2b[10];
#pragma unroll
    for (int i = 0; i < 10; ++i) {
        const int c = w + 8 * i;         // chunk of 4 k-values, c < 80
#pragma unroll
        for (int jj = 0; jj < 4; ++jj) {
            const int k = c * 4 + jj;
            float va = 0.0f, vb = 0.0f;
            if (c2 && k < H1) { va = W2[k * H2 + j0]; vb = W2[k * H2 + j0 + 50]; }
            w2a[i][jj] = va; w2b[i][jj] = vb;
        }
    }
    // ---- L4 lane mapping (waves 4-5, 96 threads) ----
    const int u4 = tid - 256;
    const bool l4act = (u4 >= 0 && u4 < 96);
    int e4 = 0, j4 = 0, kq4 = 0;
    float b4v = 0.0f;
    if (l4act) {
        e4 = u4 / 48; const int r = u4 - e4 * 48; j4 = r >> 2; kq4 = r & 3;
        b4v = b4[j4];
    }

    // ---- LDS staging (one-time) ----
    for (int i = tid; i < D * H1; i += 512) sW1[i] = W1[i];
    for (int i = tid; i < H2 * H3; i += 512) {       // W3 [k=100][j=50] -> chunked
        const int k = i / H3, j = i - k * H3;
        sW3c[(k >> 2) * 200 + j * 4 + (k & 3)] = W3[i];
    }
    for (int i = tid; i < 52 * 12; i += 512) sW4[i] = (i < H3 * D) ? W4[i] : 0.0f;
    if (tid < H1) sb1[tid] = b1[tid];
    if (tid < H2) sb2[tid] = b2[tid];
    if (tid < 52) sb3[tid] = (tid < H3) ? b3[tid] : 0.0f;
    if (tid < TT) st[tid] = t[tid];                  // t row 0 (uniform over batch)
    if (tid >= 320 && tid < 360) {                   // zero h1 pad k=300..319
        const int u = tid - 320, e = u / 20, kk = u - e * 20;
        h1[e * 320 + 300 + kk] = 0.0f;
    }
    if (tid >= 360 && tid < 364) {                   // zero h3 pad
        const int u = tid - 360;
        h3[(u >> 1) * 52 + 50 + (u & 1)] = 0.0f;
    }
    if (tid < 24) {                                  // x0 = y0[:,0,:]; out[:,0,:]
        const int e = tid / 12, j = tid - e * 12;
        const int g = (blockIdx.x * 2 + e) * (TT * D) + j;
        const float v = y0[g];
        sx[tid] = v;
        out[g]  = v;
    }
    __syncthreads();

    for (int s = 0; s < TT - 1; ++s) {
        const float dt = st[s + 1] - st[s];
#pragma unroll 1
        for (int ev = 0; ev < 4; ++ev) {
            const float* xin = ev ? sxe : sx;

            // ===== L1: 12 -> 300, col = tid, LDS weights (lane-contiguous) =====
            if (tid < H1) {
                float wv[12];
#pragma unroll
                for (int k = 0; k < 12; ++k) wv[k] = sW1[k * H1 + tid];
                const float bv = sb1[tid];
#pragma unroll
                for (int e = 0; e < 2; ++e) {
                    const v4f x0 = *(const v4f*)(xin + e * 12);
                    const v4f x1 = *(const v4f*)(xin + e * 12 + 4);
                    const v4f x2 = *(const v4f*)(xin + e * 12 + 8);
                    float a = bv;
                    a = fmaf(x0.x, wv[0], a);  a = fmaf(x0.y, wv[1], a);
                    a = fmaf(x0.z, wv[2], a);  a = fmaf(x0.w, wv[3], a);
                    a = fmaf(x1.x, wv[4], a);  a = fmaf(x1.y, wv[5], a);
                    a = fmaf(x1.z, wv[6], a);  a = fmaf(x1.w, wv[7], a);
                    a = fmaf(x2.x, wv[8], a);  a = fmaf(x2.y, wv[9], a);
                    a = fmaf(x2.z, wv[10], a); a = fmaf(x2.w, wv[11], a);
                    h1[e * 320 + tid] = lrelu(a);
                }
            }
            __syncthreads();                         // A: h1 ready

            // ===== L2: 300 -> 100, reg weights, broadcast reads, packed =====
            {
                v2f a00 = {0,0}, a01 = {0,0}, a10 = {0,0}, a11 = {0,0};
#pragma unroll
                for (int i = 0; i < 10; ++i) {
                    const int c4 = (w + 8 * i) * 4;
                    const v4f he0 = *(const v4f*)(h1 + c4);          // elem 0
                    const v4f he1 = *(const v4f*)(h1 + 320 + c4);    // elem 1
                    a00 = pkfma(lo2(he0), lo2(w2a[i]), a00);
                    a00 = pkfma(hi2(he0), hi2(w2a[i]), a00);
                    a01 = pkfma(lo2(he0), lo2(w2b[i]), a01);
                    a01 = pkfma(hi2(he0), hi2(w2b[i]), a01);
                    a10 = pkfma(lo2(he1), lo2(w2a[i]), a10);
                    a10 = pkfma(hi2(he1), hi2(w2a[i]), a10);
                    a11 = pkfma(lo2(he1), lo2(w2b[i]), a11);
                    a11 = pkfma(hi2(he1), hi2(w2b[i]), a11);
                }
                if (c2) {
                    pL2[(w * 2 + 0) * 104 + j0]      = a00.x + a00.y;
                    pL2[(w * 2 + 0) * 104 + j0 + 50] = a01.x + a01.y;
                    pL2[(w * 2 + 1) * 104 + j0]      = a10.x + a10.y;
                    pL2[(w * 2 + 1) * 104 + j0 + 50] = a11.x + a11.y;
                }
            }
            __syncthreads();                         // B: partials ready

            // ===== reduce -> h2 (8-way), waves 4-7 =====
            {
                const int u = tid - 256;
                if (u >= 0 && u < 200) {
                    const int e = u / 100, j = u - e * 100;
                    float v = sb2[j];
#pragma unroll
                    for (int q = 0; q < 8; ++q) v += pL2[(q * 2 + e) * 104 + j];
                    h2[e * 104 + j] = lrelu(v);
                }
            }
            __syncthreads();                         // C: h2 ready

            // ===== L3: 100 -> 50, waves 0-3 = k-quarters, LDS W3, packed =====
            if (w < 4 && c2) {
                v2f a0 = {0,0}, a1 = {0,0};
                for (int c = w; c < 25; c += 4) {
                    const v4f wv  = *(const v4f*)(sW3c + c * 200 + l * 4);
                    const v4f hv0 = *(const v4f*)(h2 + c * 4);
                    const v4f hv1 = *(const v4f*)(h2 + 104 + c * 4);
                    a0 = pkfma(lo2(hv0), lo2(wv), a0); a0 = pkfma(hi2(hv0), hi2(wv), a0);
                    a1 = pkfma(lo2(hv1), lo2(wv), a1); a1 = pkfma(hi2(hv1), hi2(wv), a1);
                }
                pL3[(w * 2 + 0) * 52 + l] = a0.x + a0.y;
                pL3[(w * 2 + 1) * 52 + l] = a1.x + a1.y;
            }
            __syncthreads();                         // D: pL3 ready

            // ===== reduce -> h3 (4-way), waves 6-7 =====
            {
                const int u = tid - 384;
                if (u >= 0 && u < 100) {
                    const int e = u / 50, j = u - e * 50;
                    float v = sb3[j];
#pragma unroll
                    for (int q = 0; q < 4; ++q) v += pL3[(q * 2 + e) * 52 + j];
                    h3[e * 52 + j] = lrelu(v);
                }
            }
            __syncthreads();                         // E: h3 ready

            // ===== L4: 50 -> 12, waves 4-5, shfl reduce, fused RK4 =====
            if (l4act) {
                const int kb = kq4 * 13;
                float a = 0.0f;
#pragma unroll
                for (int i = 0; i < 13; ++i)         // k<=51: h3/sW4 pads are zero
                    a = fmaf(h3[e4 * 52 + kb + i], sW4[(kb + i) * 12 + j4], a);
                a += __shfl_xor(a, 1);
                a += __shfl_xor(a, 2);
                if (kq4 == 0) {
                    a += b4v;
                    const int bi = e4 * 12 + j4;
                    const float xc = sx[bi];
                    if (ev == 0)      { sks[bi] = a;         sxe[bi] = xc + 0.5f * dt * a; }
                    else if (ev == 1) { sks[bi] += 2.f * a;  sxe[bi] = xc + 0.5f * dt * a; }
                    else if (ev == 2) { sks[bi] += 2.f * a;  sxe[bi] = xc + dt * a; }
                    else {
                        const float xn = xc + dt * (1.0f / 6.0f) * (sks[bi] + a);
                        sx[bi] = xn;
                        out[(blockIdx.x * 2 + e4) * (TT * D) + (s + 1) * D + j4] = xn;
                    }
                }
            }
            __syncthreads();                         // F: state ready
        }
    }
}

extern "C" void kernel_launch(void* const* d_in, const int* in_sizes, int n_in,
                              void* d_out, int out_size, void* d_ws, size_t ws_size,
                              hipStream_t stream) {
    const float* y0 = (const float*)d_in[0];
    const float* t  = (const float*)d_in[1];
    const float* W1 = (const float*)d_in[2];
    const float* b1 = (const float*)d_in[3];
    const float* W2 = (const float*)d_in[4];
    const float* b2 = (const float*)d_in[5];
    const float* W3 = (const float*)d_in[6];
    const float* b3 = (const float*)d_in[7];
    const float* W4 = (const float*)d_in[8];
    const float* b4 = (const float*)d_in[9];
    float* out = (float*)d_out;

    node_rk4_kernel<<<512, 512, 0, stream>>>(y0, t, W1, b1, W2, b2, W3, b3, W4, b4, out);
}